// Round 9
// baseline (69.255 us; speedup 1.0000x reference)
//
#include <hip/hip_runtime.h>

// Camera ISP fused: mosaic -> 3x3 gauss blur -> 17-knot LUT -> +noise ->
// sparse 5x5 demosaic -> bayer-parity select -> clip.
// Round 8: shuffle-free rolling-register pipeline. Each lane owns 4 output
// cols but loads a 12-col aligned mosaic window and computes its own 8-col
// noisy span (halo recomputed locally). Zero shfl, zero divergent loads;
// only DS op is the LUT gather. TDS=8 -> 4096 waves (4/SIMD).

#define TDS 8      // output rows per wave

typedef float f4a __attribute__((ext_vector_type(4), aligned(16)));
typedef float f4b __attribute__((ext_vector_type(4), aligned(8)));

__device__ __forceinline__ int refl(int i, int n) {
    return i < 0 ? -i : (i >= n ? 2 * n - 2 - i : i);
}

__device__ __forceinline__ float clip01(float x) {
    return fminf(fmaxf(x * (1.0f / 255.0f), 0.0f), 1.0f);
}

__global__ __launch_bounds__(256, 4) void camera_kernel(
    const float* __restrict__ im, const float* __restrict__ yp,
    const float* __restrict__ noise, float* __restrict__ out,
    int H, int W)
{
    __shared__ float2 s_tab[4][48];   // per-wave LUT copy (no block barrier)

    const int tid  = threadIdx.x;
    const int wv   = tid >> 6;
    const int lane = tid & 63;
    const int b    = blockIdx.z;

    const int stripes = W >> 8;                  // 256-px stripes (2)
    const int slot    = blockIdx.x * 4 + wv;
    const int stripe  = slot % stripes;
    const int gy0     = (slot / stripes) * TDS;  // even
    const int gx0     = stripe << 8;             // even
    const int x0      = gx0 + 4 * lane;          // first owned col (mult of 4)

    const size_t HW = (size_t)H * W;
    const float* p0  = im + (size_t)b * 3 * HW;  // ch0 plane
    const float* p1  = p0 + HW;                  // ch1 plane
    const float* nzb = noise + (size_t)b * HW;

    if (lane < 48) {
        int ch = lane >> 4, i = lane & 15;
        s_tab[wv][lane] = make_float2(yp[ch * 17 + i], yp[ch * 17 + i + 1]);
    }
    asm volatile("s_waitcnt lgkmcnt(0)" ::: "memory");
    const float2* tabw = s_tab[wv];

    // per-lane clamped load bases + edge case (-1: image left, +1: image right)
    const int mcase = (x0 == 0) ? -1 : ((x0 == W - 4) ? 1 : 0);
    const int cb    = (mcase < 0) ? 0 : ((mcase > 0) ? W - 12 : x0 - 4);  // even
    const int nb    = (mcase < 0) ? 0 : ((mcase > 0) ? W - 8  : x0 - 2);  // even

    const float g0 = 0.04038794f;   // 1D gauss tail (sigma=0.4, normalized)
    const float g1 = 0.91922413f;   // 1D gauss center

    auto itp = [&](float tv, int ch) -> float {  // LUT interp, input x16 scale
        float s = tv * 16.0f;
        int i = (int)s; i = i < 0 ? 0 : (i > 15 ? 15 : i);
        float2 p = tabw[ch * 16 + i];
        return fmaf(s - (float)i, p.y - p.x, p.x);
    };

    // load mosaic row t (reflect row+cols), hblur for cols x0-2..x0+5 -> hb[8]
    auto mosrow = [&](int t, float (&hb)[8]) {
        int yr = refl(t, H);                     // parity-preserving
        const float* pe = (t & 1) ? p0 : p1;     // plane for even cols
        const float* re = pe + (size_t)yr * W;
        const float* ro = re + HW;               // plane for odd cols
        f4a e0 = *(const f4a*)(re + cb);
        f4a e1 = *(const f4a*)(re + cb + 4);
        f4a e2 = *(const f4a*)(re + cb + 8);
        f4a q0 = *(const f4a*)(ro + cb);
        f4a q1 = *(const f4a*)(ro + cb + 4);
        f4a q2 = *(const f4a*)(ro + cb + 8);
        // cb even -> even offsets from even-col plane, odd from odd-col plane
        float v[12] = {e0.x, q0.y, e0.z, q0.w, e1.x, q1.y, e1.z, q1.w,
                       e2.x, q2.y, e2.z, q2.w};
        float m[12];                             // cols x0-4 .. x0+7
        if (mcase == 0) {
            #pragma unroll
            for (int j = 0; j < 12; ++j) m[j] = v[j];
        } else if (mcase < 0) {                  // x0==0: col j-4, reflect
            m[0] = v[4]; m[1] = v[3]; m[2] = v[2]; m[3] = v[1];
            m[4] = v[0]; m[5] = v[1]; m[6] = v[2]; m[7] = v[3];
            m[8] = v[4]; m[9] = v[5]; m[10] = v[6]; m[11] = v[7];
        } else {                                 // x0==W-4: cb=W-12
            m[0] = v[4]; m[1] = v[5]; m[2] = v[6]; m[3] = v[7];
            m[4] = v[8]; m[5] = v[9]; m[6] = v[10]; m[7] = v[11];
            m[8] = v[10]; m[9] = v[9]; m[10] = v[8]; m[11] = v[7];
        }
        #pragma unroll
        for (int j = 0; j < 8; ++j)
            hb[j] = fmaf(g0, m[j + 1] + m[j + 3], g1 * m[j + 2]);
    };

    float ring[5][8];                            // noisy rows, cols x0-2..x0+5
    float hrow[3][8];                            // hblur ring (static idx)
    mosrow(gy0 - 3, hrow[0]);
    mosrow(gy0 - 2, hrow[1]);
    const size_t outb = (size_t)b * 3 * HW;

    #pragma unroll
    for (int k = 0; k < TDS + 4; ++k) {
        const int r = gy0 - 2 + k;               // noisy row produced this iter
        mosrow(r + 1, hrow[(k + 2) % 3]);
        const float* hA = hrow[k % 3];
        const float* hB = hrow[(k + 1) % 3];
        const float* hC = hrow[(k + 2) % 3];

        // noise row (clamped base + static remap)
        int yr = refl(r, H);
        const float* nzr = nzb + (size_t)yr * W;
        f4b zlo = *(const f4b*)(nzr + nb);
        f4b zhi = *(const f4b*)(nzr + nb + 4);
        float nv[8] = {zlo.x, zlo.y, zlo.z, zlo.w, zhi.x, zhi.y, zhi.z, zhi.w};
        float n[8];
        if (mcase == 0) {
            #pragma unroll
            for (int j = 0; j < 8; ++j) n[j] = nv[j];
        } else if (mcase < 0) {                  // cols j-2, reflect
            n[0] = nv[2]; n[1] = nv[1];
            #pragma unroll
            for (int j = 2; j < 8; ++j) n[j] = nv[j - 2];
        } else {                                 // nb=W-8, cols 506..513
            #pragma unroll
            for (int j = 0; j < 6; ++j) n[j] = nv[j + 2];
            n[6] = nv[6]; n[7] = nv[5];
        }

        const int chE = (k & 1) ? 0 : 1;         // channel for even cols
        #pragma unroll
        for (int j = 0; j < 8; ++j) {
            float tb = fmaf(g0, hA[j] + hC[j], g1 * hB[j]);
            ring[k % 5][j] = itp(tb, (j & 1) ? chE + 1 : chE) + n[j];
        }

        if (k >= 4) {                            // demosaic row y = gy0+k-4
            const int y = gy0 + k - 4;           // parity = k&1
            float Rv[4], Gv[4], Bv[4];
            #pragma unroll
            for (int j = 0; j < 4; ++j) {
                const int cj = 2 + j;
                float c    = ring[(k - 2) % 5][cj];
                float ax1x = ring[(k - 2) % 5][cj - 1] + ring[(k - 2) % 5][cj + 1];
                float ax2x = ring[(k - 2) % 5][cj - 2] + ring[(k - 2) % 5][cj + 2];
                float ax1y = ring[(k - 3) % 5][cj] + ring[(k - 1) % 5][cj];
                float diag = ring[(k - 3) % 5][cj - 1] + ring[(k - 3) % 5][cj + 1]
                           + ring[(k - 1) % 5][cj - 1] + ring[(k - 1) % 5][cj + 1];
                float ax2y = ring[(k - 4) % 5][cj] + ring[k % 5][cj];
                const bool xO = (j & 1) != 0;
                const bool yO = (k & 1) != 0;
                float R, G, Bc;
                if (!yO && !xO) {        // p00: R=v, G=raw, B=h
                    float hh = (0.5f * ax2y - diag - ax2x + 4.f * ax1x + 5.f * c) * 0.125f;
                    float vv = (0.5f * ax2x - diag - ax2y + 4.f * ax1y + 5.f * c) * 0.125f;
                    R = vv; G = c; Bc = hh;
                } else if (!yO && xO) {  // p01: R=d, G=g, B=raw
                    float gg = (2.f * (ax1y + ax1x) - ax2y - ax2x + 4.f * c) * 0.125f;
                    float dd = (2.f * diag - 1.5f * (ax2y + ax2x) + 6.f * c) * 0.125f;
                    R = dd; G = gg; Bc = c;
                } else if (yO && !xO) {  // p10: R=raw, G=g, B=d
                    float gg = (2.f * (ax1y + ax1x) - ax2y - ax2x + 4.f * c) * 0.125f;
                    float dd = (2.f * diag - 1.5f * (ax2y + ax2x) + 6.f * c) * 0.125f;
                    R = c; G = gg; Bc = dd;
                } else {                 // p11: R=h, G=raw, B=v
                    float hh = (0.5f * ax2y - diag - ax2x + 4.f * ax1x + 5.f * c) * 0.125f;
                    float vv = (0.5f * ax2x - diag - ax2y + 4.f * ax1y + 5.f * c) * 0.125f;
                    R = hh; G = c; Bc = vv;
                }
                Rv[j] = clip01(R); Gv[j] = clip01(G); Bv[j] = clip01(Bc);
            }
            size_t o = outb + (size_t)y * W + x0;
            *(f4a*)(out + o)          = (f4a){Rv[0], Rv[1], Rv[2], Rv[3]};
            *(f4a*)(out + o + HW)     = (f4a){Gv[0], Gv[1], Gv[2], Gv[3]};
            *(f4a*)(out + o + 2 * HW) = (f4a){Bv[0], Bv[1], Bv[2], Bv[3]};
        }
    }
}

extern "C" void kernel_launch(void* const* d_in, const int* in_sizes, int n_in,
                              void* d_out, int out_size, void* d_ws, size_t ws_size,
                              hipStream_t stream) {
    const float* im    = (const float*)d_in[0];
    const float* yp    = (const float*)d_in[1];
    const float* noise = (const float*)d_in[2];
    float* out = (float*)d_out;

    const int H = 512, W = 512;
    const int B = in_sizes[2] / (H * W);         // noise is (B,1,H,W)

    const int stripes = W / 256;                 // 2
    const int slots   = stripes * (H / TDS);     // 128 wave-slots per image
    dim3 grid(slots / 4, 1, B);                  // 4 waves per 256-thread block
    camera_kernel<<<grid, 256, 0, stream>>>(im, yp, noise, out, H, W);
}

// Round 10
// 40.879 us; speedup vs baseline: 1.6941x; 1.6941x over previous
//
#include <hip/hip_runtime.h>

// Camera ISP fused: mosaic -> 3x3 gauss blur -> 17-knot LUT -> +noise ->
// sparse 5x5 demosaic -> bayer-parity select -> clip.
// Round 9: R6 rolling-register pipeline (TDS=16, 2 loads/row/lane, shfl halo)
// + explicit next-iteration load prefetch (ldmos/ldnz split from compute) and
// __launch_bounds__(256,2): VGPR headroom 128 (grid gives only 2 waves/SIMD,
// so the higher cap is free) so the unrolled loop keeps loads in flight.

#define TDS 16     // output rows per wave

typedef float f4u __attribute__((ext_vector_type(4), aligned(16)));

struct HB { float hb0, hb1, hb2, hb3, hh0, hh1; };
struct MR { f4u a, b, ae, be; };
struct NZ { f4u z; float ze0, ze1; };

__device__ __forceinline__ int refl(int i, int n) {
    return i < 0 ? -i : (i >= n ? 2 * n - 2 - i : i);
}

__device__ __forceinline__ float clip01(float x) {
    return fminf(fmaxf(x * (1.0f / 255.0f), 0.0f), 1.0f);
}

__global__ __launch_bounds__(256, 2) void camera_kernel(
    const float* __restrict__ im, const float* __restrict__ yp,
    const float* __restrict__ noise, float* __restrict__ out,
    int H, int W)
{
    __shared__ float2 s_tab[4][48];   // per-wave LUT copy (no block barrier)

    const int tid  = threadIdx.x;
    const int wv   = tid >> 6;
    const int lane = tid & 63;
    const int b    = blockIdx.z;

    const int stripes = W >> 8;                  // 256-px stripes (2)
    const int slot    = blockIdx.x * 4 + wv;
    const int stripe  = slot % stripes;
    const int gy0     = (slot / stripes) * TDS;  // even
    const int gx0     = stripe << 8;             // even
    const int x0      = gx0 + 4 * lane;

    const size_t HW = (size_t)H * W;
    const float* p0  = im + (size_t)b * 3 * HW;  // ch0 plane
    const float* p1  = p0 + HW;                  // ch1 plane
    const float* nzb = noise + (size_t)b * HW;

    if (lane < 48) {
        int ch = lane >> 4, i = lane & 15;
        s_tab[wv][lane] = make_float2(yp[ch * 17 + i], yp[ch * 17 + i + 1]);
    }
    asm volatile("s_waitcnt lgkmcnt(0)" ::: "memory");
    const float2* tabw = s_tab[wv];

    const bool l0   = (lane == 0), l63 = (lane == 63);
    const bool lInt = l0  && (gx0 != 0);         // interior stripe boundary
    const bool rInt = l63 && (x0 + 4 != W);
    const bool eInt = lInt || rInt;
    const bool eAny = l0 || l63;
    const int  xe   = l0 ? x0 - 4 : x0 + 4;      // edge mosaic halo base
    const int  xen  = l0 ? x0 - 2 : x0 + 4;      // edge noise halo base

    const float g0 = 0.04038794f;   // 1D gauss tail (sigma=0.4, normalized)
    const float g1 = 0.91922413f;   // 1D gauss center

    auto itp = [&](float tv, int ch) -> float {  // LUT interp, input x16 scale
        float s = tv * 16.0f;
        int i = (int)s; i = i < 0 ? 0 : (i > 15 ? 15 : i);
        float2 p = tabw[ch * 16 + i];
        return fmaf(s - (float)i, p.y - p.x, p.x);
    };

    // ---- raw loads (issue-only; no DS, no dependent compute) ----
    auto ldmos = [&](int t) -> MR {
        MR m;
        int yr = refl(t, H);                     // parity-preserving
        const float* pe = (t & 1) ? p0 : p1;     // plane for even cols
        const float* re = pe + (size_t)yr * W;
        const float* ro = re + HW;               // plane for odd cols
        m.a = *(const f4u*)(re + x0);
        m.b = *(const f4u*)(ro + x0);
        m.ae = m.a; m.be = m.b;                  // defined default
        if (eInt) {
            m.ae = *(const f4u*)(re + xe);
            m.be = *(const f4u*)(ro + xe);
        }
        return m;
    };
    auto ldnz = [&](int t) -> NZ {
        NZ z;
        int yr = refl(t, H);
        const float* nzr = nzb + (size_t)yr * W;
        z.z = *(const f4u*)(nzr + x0);
        z.ze0 = 0.f; z.ze1 = 0.f;
        if (eInt) {
            float2 e = *(const float2*)(nzr + xen);
            z.ze0 = e.x; z.ze1 = e.y;
        }
        return z;
    };

    // ---- hblur from raw row (shfl + fma) ----
    auto hblur = [&](const MR& q) -> HB {
        float m0 = q.a.x, m1 = q.b.y, m2 = q.a.z, m3 = q.b.w;  // cols x0..x0+3
        float ml = __shfl_up(m3, 1, 64);         // col x0-1
        float mr = __shfl_down(m0, 1, 64);       // col x0+4
        float me0 = q.ae.x, me1 = q.be.y, me2 = q.ae.z, me3 = q.be.w;
        if (l0)  ml = lInt ? me3 : m1;           // reflect: col -1 -> 1
        if (l63) mr = rInt ? me0 : m2;           // reflect: col W -> W-2
        HB h;
        h.hb0 = fmaf(g0, ml + m1, g1 * m0);
        h.hb1 = fmaf(g0, m0 + m2, g1 * m1);
        h.hb2 = fmaf(g0, m1 + m3, g1 * m2);
        h.hb3 = fmaf(g0, m2 + mr, g1 * m3);
        float hL0 = fmaf(g0, me1 + me3, g1 * me2);
        float hL1 = fmaf(g0, me2 + m0,  g1 * me3);
        float hR0 = fmaf(g0, m3 + me1,  g1 * me0);
        float hR1 = fmaf(g0, me0 + me2, g1 * me1);
        h.hh0 = l0 ? hL0 : hR0;
        h.hh1 = l0 ? hL1 : hR1;
        return h;
    };

    float ring[5][8];                            // noisy rows, cols x0-2..x0+5
    HB hA = hblur(ldmos(gy0 - 3));
    HB hB = hblur(ldmos(gy0 - 2));
    MR mN = ldmos(gy0 - 1);                      // prefetch for k=0
    NZ zN = ldnz(gy0 - 2);
    const size_t outb = (size_t)b * 3 * HW;

    #pragma unroll
    for (int k = 0; k < TDS + 4; ++k) {
        const int r = gy0 - 2 + k;               // noisy row produced this iter
        MR mC = mN;                              // consume prefetched
        NZ zC = zN;
        if (k < TDS + 3) {                       // issue next-iter loads FIRST
            mN = ldmos(r + 2);
            zN = ldnz(r + 1);
        }
        HB hC = hblur(mC);
        // vertical blur (rows r-1, r, r+1)
        float tb0 = fmaf(g0, hA.hb0 + hC.hb0, g1 * hB.hb0);
        float tb1 = fmaf(g0, hA.hb1 + hC.hb1, g1 * hB.hb1);
        float tb2 = fmaf(g0, hA.hb2 + hC.hb2, g1 * hB.hb2);
        float tb3 = fmaf(g0, hA.hb3 + hC.hb3, g1 * hB.hb3);
        float th0 = fmaf(g0, hA.hh0 + hC.hh0, g1 * hB.hh0);
        float th1 = fmaf(g0, hA.hh1 + hC.hh1, g1 * hB.hh1);
        // LUT interp; row parity = k&1 (gy0 even)
        const int chE = (k & 1) ? 0 : 1;         // channel for even cols
        const int chO = chE + 1;
        float c0 = itp(tb0, chE) + zC.z.x;
        float c1 = itp(tb1, chO) + zC.z.y;
        float c2 = itp(tb2, chE) + zC.z.z;
        float c3 = itp(tb3, chO) + zC.z.w;
        // edge-halo noisy (2 px, exec-masked to lanes 0/63)
        float e0 = 0.f, e1 = 0.f;
        if (eAny) { e0 = itp(th0, chE) + zC.ze0; e1 = itp(th1, chO) + zC.ze1; }
        // horizontal halo cols x0-2,x0-1 / x0+4,x0+5
        float hl0 = __shfl_up(c2, 1, 64);
        float hl1 = __shfl_up(c3, 1, 64);
        float hr0 = __shfl_down(c0, 1, 64);
        float hr1 = __shfl_down(c1, 1, 64);
        if (l0)  { hl0 = lInt ? e0 : c2;  hl1 = lInt ? e1 : c1; }  // reflect -2,-1 -> 2,1
        if (l63) { hr0 = rInt ? e0 : c2;  hr1 = rInt ? e1 : c1; }  // reflect W,W+1 -> W-2,W-3
        ring[k % 5][0] = hl0; ring[k % 5][1] = hl1;
        ring[k % 5][2] = c0;  ring[k % 5][3] = c1;
        ring[k % 5][4] = c2;  ring[k % 5][5] = c3;
        ring[k % 5][6] = hr0; ring[k % 5][7] = hr1;
        hA = hB; hB = hC;

        if (k >= 4) {                            // demosaic row y = gy0+k-4
            const int y = gy0 + k - 4;           // parity = k&1
            float Rv[4], Gv[4], Bv[4];
            #pragma unroll
            for (int j = 0; j < 4; ++j) {
                const int cj = 2 + j;
                float c    = ring[(k - 2) % 5][cj];
                float ax1x = ring[(k - 2) % 5][cj - 1] + ring[(k - 2) % 5][cj + 1];
                float ax2x = ring[(k - 2) % 5][cj - 2] + ring[(k - 2) % 5][cj + 2];
                float ax1y = ring[(k - 3) % 5][cj] + ring[(k - 1) % 5][cj];
                float diag = ring[(k - 3) % 5][cj - 1] + ring[(k - 3) % 5][cj + 1]
                           + ring[(k - 1) % 5][cj - 1] + ring[(k - 1) % 5][cj + 1];
                float ax2y = ring[(k - 4) % 5][cj] + ring[k % 5][cj];
                const bool xO = (j & 1) != 0;
                const bool yO = (k & 1) != 0;
                float R, G, Bc;
                if (!yO && !xO) {        // p00: R=v, G=raw, B=h
                    float hh = (0.5f * ax2y - diag - ax2x + 4.f * ax1x + 5.f * c) * 0.125f;
                    float vv = (0.5f * ax2x - diag - ax2y + 4.f * ax1y + 5.f * c) * 0.125f;
                    R = vv; G = c; Bc = hh;
                } else if (!yO && xO) {  // p01: R=d, G=g, B=raw
                    float gg = (2.f * (ax1y + ax1x) - ax2y - ax2x + 4.f * c) * 0.125f;
                    float dd = (2.f * diag - 1.5f * (ax2y + ax2x) + 6.f * c) * 0.125f;
                    R = dd; G = gg; Bc = c;
                } else if (yO && !xO) {  // p10: R=raw, G=g, B=d
                    float gg = (2.f * (ax1y + ax1x) - ax2y - ax2x + 4.f * c) * 0.125f;
                    float dd = (2.f * diag - 1.5f * (ax2y + ax2x) + 6.f * c) * 0.125f;
                    R = c; G = gg; Bc = dd;
                } else {                 // p11: R=h, G=raw, B=v
                    float hh = (0.5f * ax2y - diag - ax2x + 4.f * ax1x + 5.f * c) * 0.125f;
                    float vv = (0.5f * ax2x - diag - ax2y + 4.f * ax1y + 5.f * c) * 0.125f;
                    R = hh; G = c; Bc = vv;
                }
                Rv[j] = clip01(R); Gv[j] = clip01(G); Bv[j] = clip01(Bc);
            }
            size_t o = outb + (size_t)y * W + x0;
            *(f4u*)(out + o)          = (f4u){Rv[0], Rv[1], Rv[2], Rv[3]};
            *(f4u*)(out + o + HW)     = (f4u){Gv[0], Gv[1], Gv[2], Gv[3]};
            *(f4u*)(out + o + 2 * HW) = (f4u){Bv[0], Bv[1], Bv[2], Bv[3]};
        }
    }
}

extern "C" void kernel_launch(void* const* d_in, const int* in_sizes, int n_in,
                              void* d_out, int out_size, void* d_ws, size_t ws_size,
                              hipStream_t stream) {
    const float* im    = (const float*)d_in[0];
    const float* yp    = (const float*)d_in[1];
    const float* noise = (const float*)d_in[2];
    float* out = (float*)d_out;

    const int H = 512, W = 512;
    const int B = in_sizes[2] / (H * W);         // noise is (B,1,H,W)

    const int stripes = W / 256;                 // 2
    const int slots   = stripes * (H / TDS);     // 64 wave-slots per image
    dim3 grid(slots / 4, 1, B);                  // 4 waves per 256-thread block
    camera_kernel<<<grid, 256, 0, stream>>>(im, yp, noise, out, H, W);
}